// Round 10
// baseline (4282.675 us; speedup 1.0000x reference)
//
#include <hip/hip_runtime.h>
#include <math.h>

namespace {

constexpr int Bb = 1024;
constexpr int Tn = 64;
constexpr int Dn = 8;
constexpr int Hn = 64;
constexpr int Wn = 128;
constexpr int BT = 4;     // batch rows per block
constexpr int NT = 1024;  // 16 waves, 4 waves/SIMD, 1 block/CU
constexpr int W1S = 68;   // w1s row stride
constexpr int W2S = 132;  // w2s row stride
constexpr int YS  = 72;   // y/ys row stride: rows 8 banks apart
constexpr int HS  = 136;  // h1 row stride; halves at phys 0 / 68 (gap)
constexpr int GAP = 68;   // phys offset of h1's k=64..127 half
constexpr int KS  = 68;   // K_l inner stride

typedef float v2f __attribute__((ext_vector_type(2)));

// Tsit5 tableau
constexpr float A21 = 0.161f;
constexpr float A31 = -0.008480655492356989f, A32 = 0.335480655492357f;
constexpr float A41 = 2.8971530571054935f, A42 = -6.359448489975075f, A43 = 4.3622954328695815f;
constexpr float A51 = 5.325864828439257f, A52 = -11.748883564062828f, A53 = 7.4955393428898365f, A54 = -0.09249506636175525f;
constexpr float A61 = 5.86145544294642f, A62 = -12.92096931784711f, A63 = 8.159367898576159f, A64 = -0.071584973281401f, A65 = -0.028269050394068383f;
constexpr float Bc1 = 0.09646076681806523f, Bc2 = 0.01f, Bc3 = 0.4798896504144996f;
constexpr float Bc4 = 1.379008574103742f, Bc5 = -3.290069515436081f, Bc6 = 2.324710524099774f;

// fast transcendentals (v_exp/v_log/v_rcp based)
__device__ inline float fast_softplus(float x) {
  const float e = __expf(-fabsf(x));           // e in (0,1]
  return fmaxf(x, 0.f) + __logf(1.f + e);      // 1+e in [1,2]
}
__device__ inline float fast_tanh(float x) {
  const float xc = fminf(fmaxf(x, -10.f), 10.f);
  const float e2 = __expf(2.f * xc);
  return 1.f - __fdividef(2.f, e2 + 1.f);
}
__device__ inline float fast_sigmoid(float z) {
  return __fdividef(1.f, 1.f + __expf(-z));
}
__device__ inline float dot4(float4 w, float4 a) {
  return w.x * a.x + w.y * a.y + w.z * a.z + w.w * a.w;
}
// packed dual-FMA accumulate: acc += {w,w} * av  (v_pk_fma_f32 on CDNA)
__device__ inline v2f pkfma(v2f a, v2f b, v2f acc) {
  return __builtin_elementwise_fma(a, b, acc);
}

} // namespace

// Persistent per-batch-tile NeuralCDE integrator, 1024 threads/block.
//
// R10 vs R9 (2043us, VALUBusy 75.6%, conflicts 0, no spill): the kernel is
// VALU-ISSUE-bound; this round halves the FMA instruction count with
// v_pk_fma_f32 (packed 2xf32, via __builtin_elementwise_fma on float2):
//  * h2 -> BATCH-INTERLEAVED LDS (h2i[k'][b], k' = k + (k>=64): 1-slot gap
//    keeps the two hf wave-addresses on disjoint bank quads, preserving
//    R9's zero-conflict property). One b128 read = all 4 batches of one k
//    (same 64 reads/thread/stage as R9), feeding 2 pk_fma instead of 4 FMA.
//  * L1/L2 accumulate in float2 along k (hadd once at the end): 64->32 and
//    128->64 FMA insts respectively.
//  * everything else (w3r regs, gap h1, fused update, 3 bar/stage) = R9.
__global__ __launch_bounds__(NT, 4)
void ncde_kernel(const float* __restrict__ xs,
                 const float* __restrict__ iw1, const float* __restrict__ ib1,
                 const float* __restrict__ iw2, const float* __restrict__ ib2,
                 const float* __restrict__ iw3, const float* __restrict__ ib3,
                 const float* __restrict__ vw1, const float* __restrict__ vb1,
                 const float* __restrict__ vw2, const float* __restrict__ vb2,
                 const float* __restrict__ vw3, const float* __restrict__ vb3,
                 const float* __restrict__ lw,  const float* __restrict__ lb,
                 float* __restrict__ out)
{
  __shared__ float w1s[Wn][W1S];          // 34.8 KB: w1s[o][k] row-major
  __shared__ float w2s[Wn][W2S];          // 67.6 KB: w2s[o][k] row-major
  __shared__ float xs_l[BT][Tn * Dn];     // 8 KB control path
  __shared__ float y_l[BT][YS];           // current state
  __shared__ float ys_l[BT][YS];          // stage input
  __shared__ float K_l[6][BT][KS];        // stage slopes
  __shared__ float h1_l[BT][HS];          // gap layout: [0..63] + [68..131]
  __shared__ float h2i[129 * 4 + 4];      // batch-interleaved: h2i[k'*4+b]
  __shared__ float lw_l[Hn];

  const int tid = threadIdx.x;
  const int b12 = tid & 3;          // L1/L2 batch row (tid<512)
  const int oL  = (tid >> 2) & 127; // L1/L2 output neuron (tid<512)
  const int pOL = oL + (oL >= 64 ? 4 : 0);   // gap phys index into h1
  const int pK2 = (oL + (oL >= 64 ? 1 : 0)) * 4 + b12;  // h2i write slot
  const int hf  = tid & 1;          // L3 k-half
  const int d   = (tid >> 1) & 7;   // L3 data-dim (vw3 row = tid>>1 = h3*8+d)
  const int h3  = tid >> 4;         // L3 hidden index, 0..63
  const int b0  = blockIdx.x * BT;

  const float b1r = vb1[oL];
  const float b2r = vb2[oL];
  const float b3r = vb3[tid >> 1];
  const float lb0 = lb[0];

  // ---- w3 half-row -> registers, ONCE (contiguous 256B per lane) ----
  float w3r[64];
  {
    const float4* p = (const float4*)(vw3 + tid * 64);  // (tid>>1)*128+(tid&1)*64
    #pragma unroll
    for (int i = 0; i < 16; ++i) {
      float4 v = p[i];
      w3r[4*i+0] = v.x; w3r[4*i+1] = v.y; w3r[4*i+2] = v.z; w3r[4*i+3] = v.w;
    }
  }

  // ---- stage w1/w2 row-major into LDS ----
  #pragma unroll
  for (int i = 0; i < 8; ++i) {           // 8192 f32 / 1024 threads
    const int e = i * NT + tid;           // e = o*64 + k
    w1s[e >> 6][e & 63] = vw1[e];
  }
  #pragma unroll
  for (int i = 0; i < 16; ++i) {          // 16384 f32 / 1024 threads
    const int e = i * NT + tid;           // e = o*128 + k
    w2s[e >> 7][e & 127] = vw2[e];
  }
  // ---- this block's xs rows (512 x float4 = 8 KB) ----
  if (tid < 512)
    ((float4*)&xs_l[0][0])[tid] = ((const float4*)(xs + b0 * Tn * Dn))[tid];
  if (tid < Hn) lw_l[tid] = lw[tid];
  __syncthreads();

  // ---- initial MLP (relu, relu, identity): y0 = mlp(xs[:,0]) ----
  if (tid < 512) {
    const int b = tid >> 7, oo = tid & 127;
    float acc = ib1[oo];
    #pragma unroll
    for (int k = 0; k < Dn; ++k) acc += iw1[oo * Dn + k] * xs_l[b][k];
    h1_l[b][oo + (oo >= 64 ? 4 : 0)] = fmaxf(acc, 0.f);
  }
  __syncthreads();
  if (tid < 512) {
    const int b = tid >> 7, oo = tid & 127;
    float acc = ib2[oo];
    const float4* wrow = (const float4*)(iw2 + oo * Wn);
    #pragma unroll
    for (int k4 = 0; k4 < 16; ++k4)
      acc += dot4(wrow[k4], *(const float4*)&h1_l[b][k4 * 4]);
    #pragma unroll
    for (int k4 = 0; k4 < 16; ++k4)
      acc += dot4(wrow[16 + k4], *(const float4*)&h1_l[b][GAP + k4 * 4]);
    h2i[(oo + (oo >= 64 ? 1 : 0)) * 4 + b] = fmaxf(acc, 0.f);
  }
  __syncthreads();
  if (tid < BT * Hn) {
    const int b = tid >> 6, h = tid & (Hn - 1);
    float acc = ib3[h];
    for (int k = 0; k < Wn; ++k)
      acc += iw3[h * Wn + k] * h2i[(k + (k >= 64 ? 1 : 0)) * 4 + b];
    y_l[b][h]  = acc;
    ys_l[b][h] = acc;
  }
  __syncthreads();

  auto readout = [&](int t) {
    if (tid < BT * Hn) {
      const int wv = tid >> 6, h = tid & (Hn - 1);
      float p = lw_l[h] * y_l[wv][h];
      #pragma unroll
      for (int off = 32; off > 0; off >>= 1) p += __shfl_xor(p, off, 64);
      if (h == 0) out[(b0 + wv) * Tn + t] = fast_sigmoid(p + lb0);
    }
  };
  readout(0);

  // ---- 63 Tsit5 steps; per stage: L1 -> bar -> L2 -> bar -> L3+update -> bar
  #pragma unroll 1
  for (int t = 0; t < Tn - 1; ++t) {
    float dxr[BT];

    #pragma unroll 1
    for (int s = 0; s < 6; ++s) {
      if (s == 0) {
        #pragma unroll
        for (int b = 0; b < BT; ++b)
          dxr[b] = xs_l[b][(t + 1) * Dn + d] - xs_l[b][t * Dn + d];
      }

      // ---- vf layer 1 (tid<512): packed 64-k dot ----
      if (tid < 512) {
        v2f acc2 = {0.f, 0.f};
        #pragma unroll
        for (int k4 = 0; k4 < 16; ++k4) {
          const float4 wv = *(const float4*)&w1s[oL][k4 * 4];
          const float4 av = *(const float4*)&ys_l[b12][k4 * 4];
          const v2f* wp = (const v2f*)&wv;
          const v2f* ap = (const v2f*)&av;
          acc2 = pkfma(wp[0], ap[0], acc2);
          acc2 = pkfma(wp[1], ap[1], acc2);
        }
        h1_l[b12][pOL] = fast_softplus(acc2.x + acc2.y + b1r);
      }
      __syncthreads();
      // ---- vf layer 2 (tid<512): packed 128-k dot, interleaved write ----
      if (tid < 512) {
        v2f acc2 = {0.f, 0.f};
        #pragma unroll
        for (int k4 = 0; k4 < 16; ++k4) {
          const float4 wv = *(const float4*)&w2s[oL][k4 * 4];
          const float4 av = *(const float4*)&h1_l[b12][k4 * 4];
          const v2f* wp = (const v2f*)&wv;
          const v2f* ap = (const v2f*)&av;
          acc2 = pkfma(wp[0], ap[0], acc2);
          acc2 = pkfma(wp[1], ap[1], acc2);
        }
        #pragma unroll
        for (int k4 = 0; k4 < 16; ++k4) {
          const float4 wv = *(const float4*)&w2s[oL][64 + k4 * 4];
          const float4 av = *(const float4*)&h1_l[b12][GAP + k4 * 4];
          const v2f* wp = (const v2f*)&wv;
          const v2f* ap = (const v2f*)&av;
          acc2 = pkfma(wp[0], ap[0], acc2);
          acc2 = pkfma(wp[1], ap[1], acc2);
        }
        h2i[pK2] = fast_softplus(acc2.x + acc2.y + b2r);
      }
      __syncthreads();
      // ---- vf layer 3 (all 1024): packed batch-pairs, fused update ----
      {
        v2f A01 = {0.f, 0.f}, A23 = {0.f, 0.f};
        const float* h2b = &h2i[(hf ? 65 : 0) * 4];
        #pragma unroll
        for (int c = 0; c < 64; ++c) {
          const float w = w3r[c];
          const v2f wv = {w, w};
          const float4 av = *(const float4*)(h2b + 4 * c);  // 4 batches of k
          const v2f* ap = (const v2f*)&av;
          A01 = pkfma(wv, ap[0], A01);
          A23 = pkfma(wv, ap[1], A23);
        }
        float a0 = A01.x, a1 = A01.y, a2 = A23.x, a3 = A23.y;
        // join k-halves (pair lane), tanh, einsum over d
        a0 += __shfl_xor(a0, 1, 64);
        a1 += __shfl_xor(a1, 1, 64);
        a2 += __shfl_xor(a2, 1, 64);
        a3 += __shfl_xor(a3, 1, 64);
        float p0 = fast_tanh(a0 + b3r) * dxr[0];
        float p1 = fast_tanh(a1 + b3r) * dxr[1];
        float p2 = fast_tanh(a2 + b3r) * dxr[2];
        float p3 = fast_tanh(a3 + b3r) * dxr[3];
        p0 += __shfl_xor(p0, 2, 64); p0 += __shfl_xor(p0, 4, 64); p0 += __shfl_xor(p0, 8, 64);
        p1 += __shfl_xor(p1, 2, 64); p1 += __shfl_xor(p1, 4, 64); p1 += __shfl_xor(p1, 8, 64);
        p2 += __shfl_xor(p2, 2, 64); p2 += __shfl_xor(p2, 4, 64); p2 += __shfl_xor(p2, 8, 64);
        p3 += __shfl_xor(p3, 2, 64); p3 += __shfl_xor(p3, 4, 64); p3 += __shfl_xor(p3, 8, 64);
        const int wl = tid & 15;
        if (wl < BT) {
          const float kv = (wl == 0) ? p0 : (wl == 1) ? p1 : (wl == 2) ? p2 : p3;
          K_l[s][wl][h3] = kv;
          float v = y_l[wl][h3];
          if (s == 0)      v += A21 * kv;
          else if (s == 1) v += A31 * K_l[0][wl][h3] + A32 * kv;
          else if (s == 2) v += A41 * K_l[0][wl][h3] + A42 * K_l[1][wl][h3] + A43 * kv;
          else if (s == 3) v += A51 * K_l[0][wl][h3] + A52 * K_l[1][wl][h3]
                              + A53 * K_l[2][wl][h3] + A54 * kv;
          else if (s == 4) v += A61 * K_l[0][wl][h3] + A62 * K_l[1][wl][h3]
                              + A63 * K_l[2][wl][h3] + A64 * K_l[3][wl][h3] + A65 * kv;
          else             v += Bc1 * K_l[0][wl][h3] + Bc2 * K_l[1][wl][h3]
                              + Bc3 * K_l[2][wl][h3] + Bc4 * K_l[3][wl][h3]
                              + Bc5 * K_l[4][wl][h3] + Bc6 * kv;
          if (s < 5) {
            ys_l[wl][h3] = v;
          } else {
            y_l[wl][h3]  = v;
            ys_l[wl][h3] = v;
          }
        }
      }
      __syncthreads();
    }
    readout(t + 1);
  }
}

extern "C" void kernel_launch(void* const* d_in, const int* in_sizes, int n_in,
                              void* d_out, int out_size, void* d_ws, size_t ws_size,
                              hipStream_t stream) {
  const float* xs  = (const float*)d_in[1];
  const float* iw1 = (const float*)d_in[2];
  const float* ib1 = (const float*)d_in[3];
  const float* iw2 = (const float*)d_in[4];
  const float* ib2 = (const float*)d_in[5];
  const float* iw3 = (const float*)d_in[6];
  const float* ib3 = (const float*)d_in[7];
  const float* vw1 = (const float*)d_in[8];
  const float* vb1 = (const float*)d_in[9];
  const float* vw2 = (const float*)d_in[10];
  const float* vb2 = (const float*)d_in[11];
  const float* vw3 = (const float*)d_in[12];
  const float* vb3 = (const float*)d_in[13];
  const float* lw  = (const float*)d_in[14];
  const float* lb  = (const float*)d_in[15];
  float* out = (float*)d_out;

  ncde_kernel<<<Bb / BT, NT, 0, stream>>>(xs, iw1, ib1, iw2, ib2, iw3, ib3,
                                          vw1, vb1, vw2, vb2, vw3, vb3, lw, lb, out);
}